// Round 9
// baseline (284.838 us; speedup 1.0000x reference)
//
#include <hip/hip_runtime.h>

// Problem constants (fixed by setup_inputs in the reference):
//   feature_map: (1, 256, 256, 256) fp32, NHWC
//   rois:        (2000, 5) int32  [batch, x, y, w, h]
//   pool_size:   7
#define FH 256
#define FW 256
#define FC 256
#define POOL 7

// Round-9 theory: every prior variant pushed the same ~500 MB (401 MB tap
// reads + 98 MB writes) through the per-CU vector-memory pipe at its
// ~10-11 B/cyc/CU ceiling (m13) -> constant 72 us regardless of cache level
// (round 6: FETCH 170->28 MB, no time change; warm passes: 2.4 MB, still
// 72 us). Fix: read each fm byte from global ONCE into LDS and serve the
// ~5x tap overlap from the separate 69 TB/s LDS pipe.
// Global traffic: ~76 MB staging + 33 MB ROI scan + 98 MB writes = 207 MB.

#define TS 16                    // tile size in px
#define TP 17                    // staged px span (tile + 1-px halo; a cell's
                                 // 4 taps are a 2x2 adjacent-pixel block)
#define CQ 64                    // channels per block (quarter of 256)
#define NCQ (FC/CQ)              // 4
#define TILES_X (FW/TS)          // 16
#define NTILES (TILES_X*(FH/TS)) // 256
#define RB 64                    // ROIs per scan batch
#define QCAP (RB*POOL*POOL)      // exact queue bound: 3136

typedef float f32x4 __attribute__((ext_vector_type(4)));

// Single stateless kernel (no workspace, no global atomics, write-once
// output) — replay-safe. Ownership: a cell belongs to the tile containing
// its (y0,x0) anchor tap; the 4 channel-quarter blocks of that tile write
// disjoint 256 B slices. Scan logic identical to round 6 (harness-verified).
__global__ __launch_bounds__(256) void roi_pool_lds(
    const float* __restrict__ fm,
    const int*   __restrict__ rois,
    float*       __restrict__ out,
    int n_rois)
{
    __shared__ float tilebuf[TP*TP*CQ];     // 73,984 B (gfx950 allows >64 KB)
    __shared__ unsigned short q[QCAP];      // 6,272 B packed (rl<<6|pj<<3|pi)
    __shared__ int lroi[RB];                // packed x|y<<8|w<<16|h<<24
    __shared__ int qn;                      // total ~80.5 KB -> 2 blocks/CU

    // Chunked XCD swizzle (grid=1024, divisible by 8): each XCD owns 32
    // contiguous tiles -> adjacent-tile halo overlap stays in its L2.
    int nwg  = gridDim.x;
    int qd   = nwg >> 3;
    int rr   = nwg & 7;
    int xcd  = blockIdx.x & 7;
    int slt  = blockIdx.x >> 3;
    int base = (xcd < rr) ? xcd*(qd+1) : rr*(qd+1) + (xcd-rr)*qd;
    int lb   = base + slt;

    int cq      = lb & (NCQ-1);             // channel quarter
    int tile_id = lb >> 2;                  // NCQ == 4
    int tly = tile_id / TILES_X;
    int tlx = tile_id % TILES_X;

    int tid  = threadIdx.x;
    int lane = tid & 63;
    int wav  = tid >> 6;

    // ---- stage 17x17 px x 64 ch from global (each fm byte read once) ----
    {
        int s = tid & 15;                   // 16 B sub-chunk of a 256 B slice
        for (int p = tid >> 4; p < TP*TP; p += 16) {
            int ly = p / TP, lx = p % TP;
            int gy = min(tly*TS + ly, FH-1);   // clamp only matters at edge
            int gx = min(tlx*TS + lx, FW-1);   // tiles; clamped px never used
            const f32x4* src = (const f32x4*)(fm + ((size_t)gy*FW + gx)*FC + cq*CQ) + s;
            *(f32x4*)&tilebuf[p*CQ + s*4] = *src;
        }
    }

    int nb = (n_rois + RB - 1) / RB;
    for (int b = 0; b < nb; ++b) {
        __syncthreads();                    // staging done / prev drain done
        if (tid == 0) qn = 0;
        __syncthreads();

        // ---- scan: wave 0, one ROI per lane (round-6 proven logic) ----
        if (tid < RB) {
            int roi = b*RB + tid;
            if (roi < n_rois) {
                int rx = rois[roi*5+1];
                int ry = rois[roi*5+2];
                int rw = rois[roi*5+3];
                int rh = rois[roi*5+4];
                lroi[tid] = rx | (ry<<8) | (rw<<16) | (rh<<24);
                int yb = 0, xb = 0;
                for (int p = 0; p < POOL; ++p) {
                    float fy = fminf(fmaxf(((float)p+0.5f)*((float)rh/(float)POOL)-0.5f, 0.f), (float)rh-1.f);
                    int y0 = ry + (int)floorf(fy);
                    if ((y0 >> 4) == tly) yb |= 1 << p;
                    float fx = fminf(fmaxf(((float)p+0.5f)*((float)rw/(float)POOL)-0.5f, 0.f), (float)rw-1.f);
                    int x0 = rx + (int)floorf(fx);
                    if ((x0 >> 4) == tlx) xb |= 1 << p;
                }
                if (yb && xb) {
                    int cnt = __popc(yb) * __popc(xb);
                    int pos = atomicAdd(&qn, cnt);      // LDS atomic
                    for (int pj = 0; pj < POOL; ++pj) if (yb & (1<<pj))
                        for (int pi = 0; pi < POOL; ++pi) if (xb & (1<<pi))
                            q[pos++] = (unsigned short)((tid<<6)|(pj<<3)|pi);
                }
            }
        }
        __syncthreads();

        // ---- drain: 4 cells per wave-iter, 16 lanes x 16 B per cell ----
        int n = qn;
        for (int i = wav*4; i < n; i += 16) {
            int e = i + (lane >> 4);
            if (e < n) {
                int pk = q[e];
                int rl = pk >> 6;
                int pj = (pk >> 3) & 7;
                int pi = pk & 7;
                int pr = lroi[rl];
                int rx = pr & 255, ry = (pr>>8) & 255, rw = (pr>>16) & 255, rh = (pr>>24) & 255;

                float fy = fminf(fmaxf(((float)pj+0.5f)*((float)rh/(float)POOL)-0.5f, 0.f), (float)rh-1.f);
                int   j0 = (int)floorf(fy);
                int   j1 = min(j0+1, rh-1);
                float wy = fy - (float)j0;
                float fx = fminf(fmaxf(((float)pi+0.5f)*((float)rw/(float)POOL)-0.5f, 0.f), (float)rw-1.f);
                int   i0 = (int)floorf(fx);
                int   i1 = min(i0+1, rw-1);
                float wx = fx - (float)i0;

                int ly0 = ry + j0 - tly*TS;     // in [0,15] (anchor in tile)
                int ly1 = ry + j1 - tly*TS;     // in [0,16] (halo staged)
                int lx0 = rx + i0 - tlx*TS;
                int lx1 = rx + i1 - tlx*TS;

                int s = lane & 15;
                f32x4 a  = *(const f32x4*)&tilebuf[(ly0*TP+lx0)*CQ + s*4];
                f32x4 bb = *(const f32x4*)&tilebuf[(ly0*TP+lx1)*CQ + s*4];
                f32x4 c  = *(const f32x4*)&tilebuf[(ly1*TP+lx0)*CQ + s*4];
                f32x4 d  = *(const f32x4*)&tilebuf[(ly1*TP+lx1)*CQ + s*4];

                float owx = 1.f - wx, owy = 1.f - wy;
                f32x4 top = a*owx + bb*wx;
                f32x4 bot = c*owx + d*wx;
                f32x4 res = top*owy + bot*wy;

                int roi  = b*RB + rl;
                int cell = (roi*POOL + pj)*POOL + pi;
                __builtin_nontemporal_store(res, (f32x4*)(out + (size_t)cell*FC + cq*CQ) + s);
            }
        }
    }
}

extern "C" void kernel_launch(void* const* d_in, const int* in_sizes, int n_in,
                              void* d_out, int out_size, void* d_ws, size_t ws_size,
                              hipStream_t stream) {
    const float* fm   = (const float*)d_in[0];
    const int*   rois = (const int*)d_in[1];
    // d_in[2] is pool_size (==7), fixed by the problem; hardcoded as POOL.
    float* out = (float*)d_out;
    (void)d_ws; (void)ws_size;

    int n_rois = in_sizes[1] / 5;

    int grid = NTILES * NCQ;    // 1024 blocks, data-independent
    roi_pool_lds<<<grid, 256, 0, stream>>>(fm, rois, out, n_rois);
}

// Round 10
// 209.284 us; speedup vs baseline: 1.3610x; 1.3610x over previous
//
#include <hip/hip_runtime.h>

// Problem constants (fixed by setup_inputs in the reference):
//   feature_map: (1, 256, 256, 256) fp32, NHWC
//   rois:        (2000, 5) int32  [batch, x, y, w, h]
//   pool_size:   7
#define FH 256
#define FW 256
#define FC 256
#define POOL 7

// Round-10: tile-colocated execution with R2-grade parallelism.
// - Work item = 8x8-px tile (1024 tiles). A cell belongs to the tile of its
//   (y0,x0) anchor tap; its 4 taps are a 2x2 adjacent block -> tile+1px halo
//   (9x9 px ~= 83 KB) is the whole read set.
// - 256 persistent blocks (1 per CU) x 1024 threads; global-atomic ticket
//   (work stealing) kills the per-tile load imbalance that sank rounds 6/9.
// - Taps read from GLOBAL (L2-hot: 32 live tiles/XCD ~= 2.7 MB < 4 MiB L2),
//   not LDS-staged (staging cost sank round 9). 16 waves drain one cell
//   each in parallel with the proven round-2 inner body.
// - Ticket counter in d_ws, reset by hipMemsetAsync each launch: replay-safe.

#define TS 8                      // tile size in px
#define TILES_X (FW / TS)         // 32
#define NTILES (TILES_X * (FH / TS))  // 1024
#define RB 256                    // ROIs per scan batch
#define QCAP (RB * POOL * POOL)   // exact worst-case queue: 12544

typedef float f32x4 __attribute__((ext_vector_type(4)));

__global__ __launch_bounds__(1024) void roi_pool_ws(
    const float* __restrict__ fm,
    const int*   __restrict__ rois,
    float*       __restrict__ out,
    int n_rois,
    int* __restrict__ ticket)
{
    __shared__ unsigned short q[QCAP];   // packed (rl<<6 | pj<<3 | pi)
    __shared__ int lroi[RB];             // packed x | y<<8 | w<<16 | h<<24
    __shared__ int qn;
    __shared__ int sh_tk;

    int tid  = threadIdx.x;
    int lane = tid & 63;
    int wav  = tid >> 6;                 // 16 waves per block

    for (;;) {
        if (tid == 0) sh_tk = atomicAdd(ticket, 1);   // device-scope, ~1.3k total
        __syncthreads();
        int tk = sh_tk;
        if (tk >= NTILES) break;         // uniform exit
        int tly = tk / TILES_X;
        int tlx = tk % TILES_X;

        int nb = (n_rois + RB - 1) / RB;
        for (int b = 0; b < nb; ++b) {
            __syncthreads();             // prev drain / prev-ticket users done
            if (tid == 0) qn = 0;
            __syncthreads();

            // ---- scan: threads 0..RB-1, one ROI each (bitmask ownership,
            //      single code site -> every cell claimed exactly once) ----
            int roi = b * RB + tid;
            if (tid < RB && roi < n_rois) {
                int rx = rois[roi*5+1];
                int ry = rois[roi*5+2];
                int rw = rois[roi*5+3];
                int rh = rois[roi*5+4];
                lroi[tid] = rx | (ry<<8) | (rw<<16) | (rh<<24);
                int yb = 0, xb = 0;
                for (int p = 0; p < POOL; ++p) {
                    float fy = fminf(fmaxf(((float)p+0.5f)*((float)rh/(float)POOL)-0.5f, 0.f), (float)rh-1.f);
                    int y0 = ry + (int)floorf(fy);
                    if ((y0 / TS) == tly) yb |= 1 << p;
                    float fx = fminf(fmaxf(((float)p+0.5f)*((float)rw/(float)POOL)-0.5f, 0.f), (float)rw-1.f);
                    int x0 = rx + (int)floorf(fx);
                    if ((x0 / TS) == tlx) xb |= 1 << p;
                }
                if (yb && xb) {
                    int cnt = __popc(yb) * __popc(xb);
                    int pos = atomicAdd(&qn, cnt);       // LDS atomic
                    for (int pj = 0; pj < POOL; ++pj) if (yb & (1<<pj))
                        for (int pi = 0; pi < POOL; ++pi) if (xb & (1<<pi))
                            q[pos++] = (unsigned short)((tid<<6)|(pj<<3)|pi);
                }
            }
            __syncthreads();

            // ---- drain: 16 waves, ONE CELL PER WAVE in parallel (R2 body;
            //      reads hit L2: this block's 9x9-px set is hot) ----
            int n = qn;
            for (int i = wav; i < n; i += 16) {
                int pk = q[i];                            // wave-uniform
                int rl = pk >> 6;
                int pj = (pk >> 3) & 7;
                int pi = pk & 7;
                int pr = lroi[rl];
                int rx = pr & 255, ry = (pr>>8) & 255, rw = (pr>>16) & 255, rh = (pr>>24) & 255;

                float lfh = (float)rh;
                float fy  = fminf(fmaxf(((float)pj+0.5f)*(lfh/(float)POOL)-0.5f, 0.f), lfh-1.f);
                int   j0 = (int)floorf(fy);
                int   j1 = min(j0+1, rh-1);
                float wy = fy - (float)j0;
                int   y0 = ry + j0;
                int   y1 = ry + j1;

                float lfw = (float)rw;
                float fx  = fminf(fmaxf(((float)pi+0.5f)*(lfw/(float)POOL)-0.5f, 0.f), lfw-1.f);
                int   i0 = (int)floorf(fx);
                int   i1 = min(i0+1, rw-1);
                float wx = fx - (float)i0;
                int   x0 = rx + i0;
                int   x1 = rx + i1;

                const f32x4* p00 = (const f32x4*)(fm + ((size_t)y0*FW + x0)*FC) + lane;
                const f32x4* p01 = (const f32x4*)(fm + ((size_t)y0*FW + x1)*FC) + lane;
                const f32x4* p10 = (const f32x4*)(fm + ((size_t)y1*FW + x0)*FC) + lane;
                const f32x4* p11 = (const f32x4*)(fm + ((size_t)y1*FW + x1)*FC) + lane;

                f32x4 a  = *p00;
                f32x4 bb = *p01;
                f32x4 c  = *p10;
                f32x4 d  = *p11;

                float owx = 1.f - wx, owy = 1.f - wy;
                f32x4 top = a*owx + bb*wx;
                f32x4 bot = c*owx + d*wx;
                f32x4 res = top*owy + bot*wy;

                int roi2 = b*RB + rl;
                int cell = (roi2*POOL + pj)*POOL + pi;
                // Write-once output: evict-first, don't pollute L2.
                __builtin_nontemporal_store(res, (f32x4*)(out + (size_t)cell*FC) + lane);
            }
        }
        __syncthreads();   // all waves done with q/lroi before next ticket
    }
}

// Fallback if no workspace: proven round-2 direct kernel.
__global__ __launch_bounds__(256) void roi_pool_direct(
    const float* __restrict__ fm,
    const int*   __restrict__ rois,
    float*       __restrict__ out,
    int n_rois)
{
    int t = blockIdx.x * blockDim.x + (int)threadIdx.x;
    int total = n_rois * POOL * POOL * (FC / 4);
    if (t >= total) return;

    int lane = t & 63;
    int cell = t >> 6;
    int pi   = cell % POOL;
    int tmp  = cell / POOL;
    int pj   = tmp % POOL;
    int roi  = tmp / POOL;

    int rx = rois[roi*5+1];
    int ry = rois[roi*5+2];
    int rw = rois[roi*5+3];
    int rh = rois[roi*5+4];

    float lfh = (float)rh;
    float fy  = fminf(fmaxf(((float)pj+0.5f)*(lfh/(float)POOL)-0.5f, 0.f), lfh-1.f);
    int   j0 = (int)floorf(fy);
    int   j1 = min(j0+1, rh-1);
    float wy = fy - (float)j0;
    int   y0 = ry + j0;
    int   y1 = ry + j1;

    float lfw = (float)rw;
    float fx  = fminf(fmaxf(((float)pi+0.5f)*(lfw/(float)POOL)-0.5f, 0.f), lfw-1.f);
    int   i0 = (int)floorf(fx);
    int   i1 = min(i0+1, rw-1);
    float wx = fx - (float)i0;
    int   x0 = rx + i0;
    int   x1 = rx + i1;

    const f32x4* p00 = (const f32x4*)(fm + ((size_t)y0*FW + x0)*FC) + lane;
    const f32x4* p01 = (const f32x4*)(fm + ((size_t)y0*FW + x1)*FC) + lane;
    const f32x4* p10 = (const f32x4*)(fm + ((size_t)y1*FW + x0)*FC) + lane;
    const f32x4* p11 = (const f32x4*)(fm + ((size_t)y1*FW + x1)*FC) + lane;

    f32x4 a  = *p00;
    f32x4 bb = *p01;
    f32x4 c  = *p10;
    f32x4 d  = *p11;

    float owx = 1.f - wx, owy = 1.f - wy;
    f32x4 top = a*owx + bb*wx;
    f32x4 bot = c*owx + d*wx;
    f32x4 res = top*owy + bot*wy;

    __builtin_nontemporal_store(res, (f32x4*)(out + (size_t)cell*FC) + lane);
}

extern "C" void kernel_launch(void* const* d_in, const int* in_sizes, int n_in,
                              void* d_out, int out_size, void* d_ws, size_t ws_size,
                              hipStream_t stream) {
    const float* fm   = (const float*)d_in[0];
    const int*   rois = (const int*)d_in[1];
    // d_in[2] is pool_size (==7), fixed by the problem; hardcoded as POOL.
    float* out = (float*)d_out;

    int n_rois = in_sizes[1] / 5;

    if (d_ws == nullptr || ws_size < sizeof(int)) {
        int n_cells = n_rois * POOL * POOL;
        int total = n_cells * (FC / 4);
        int grid  = (total + 255) / 256;
        roi_pool_direct<<<grid, 256, 0, stream>>>(fm, rois, out, n_rois);
        return;
    }

    // Replay-safe ticket reset (capturable async op, same family the
    // harness's own reset() uses).
    hipMemsetAsync(d_ws, 0, sizeof(int), stream);

    roi_pool_ws<<<256, 1024, 0, stream>>>(fm, rois, out, n_rois, (int*)d_ws);
}